// Round 1
// baseline (193.408 us; speedup 1.0000x reference)
//
#include <hip/hip_runtime.h>
#include <stdint.h>

typedef uint64_t u64;
typedef uint32_t u32;

#define NB    8
#define NQ    4096
#define NKEY  4096
#define HD    64
#define CV    64
#define KSEL  16
#define NWAVE 4
#define KPP   (NKEY / NWAVE)   /* 1024 keys per partition-wave */
#define CAP   32               /* per-lane LDS candidate buffer slots */
#define QPB   64               /* queries per block (= lanes) */
#define CHUNK 8

/* padding entry: d2=+inf, idx=max  (fp32 bits of nonneg floats are monotone as u32) */
#define PADV ((((u64)0x7F800000u) << 32) | (u64)0xFFFFFFFFu)

/* fully-unrolled bitonic sort, ascending; all indices compile-time after unroll */
__device__ __forceinline__ void sort32(u64 v[CAP]) {
#pragma unroll
    for (int k = 2; k <= CAP; k <<= 1) {
#pragma unroll
        for (int j = k >> 1; j > 0; j >>= 1) {
#pragma unroll
            for (int i = 0; i < CAP; i++) {
                const int l = i ^ j;
                if (l > i) {
                    const bool up = ((i & k) == 0);
                    const u64 a = v[i], b = v[l];
                    const bool doswap = up ? (a > b) : (a < b);
                    v[i] = doswap ? b : a;
                    v[l] = doswap ? a : b;
                }
            }
        }
    }
}

extern "C" __global__ void __launch_bounds__(256, 2)
sparse_bev_attn_kernel(const float* __restrict__ qg,
                       const float* __restrict__ kg,
                       const float* __restrict__ vg,
                       const float* __restrict__ qw,
                       const float* __restrict__ qbias,
                       const float* __restrict__ kw,
                       const float* __restrict__ kbias,
                       float* __restrict__ outg)
{
    /* 64 KB arena: phase-1 per-lane candidate buffers.
       Phase-2 overlays sidx/sw onto wave-0 slots 16..31 (unused after final compact). */
    __shared__ u64 sbuf[NWAVE][CAP][QPB];
    u32*   sidx = (u32*)&sbuf[0][16][0];   /* [QPB][KSEL] = 4 KB */
    float* sw_  = (float*)&sbuf[0][24][0]; /* [QPB][KSEL] = 4 KB */

    const int tid  = threadIdx.x;
    const int wv   = tid >> 6;         /* key partition */
    const int lane = tid & 63;         /* query within block */
    const int b    = blockIdx.x >> 6;
    const int q0   = (blockIdx.x & 63) << 6;
    const int qi   = q0 + lane;

    const float2* kp = (const float2*)(kg + (size_t)b * NKEY * 2);
    const float2  qc = *(const float2*)(qg + ((size_t)b * NQ + qi) * 2);
    const float qx = qc.x, qy = qc.y;

    int   cnt = 0;
    float thr = __builtin_inff();
    const int jb = __builtin_amdgcn_readfirstlane(wv * KPP); /* uniform -> s_load keys */

    auto compact = [&]() {
        u64 t[CAP];
#pragma unroll
        for (int s = 0; s < CAP; s++) {
            const u64 x = sbuf[wv][s][lane];       /* stale slots masked below */
            t[s] = (s < cnt) ? x : PADV;
        }
        sort32(t);
#pragma unroll
        for (int s = 0; s < KSEL; s++) sbuf[wv][s][lane] = t[s];
        cnt = KSEL;
        thr = __uint_as_float((u32)(t[KSEL - 1] >> 32)); /* +inf if <16 real entries */
    };

    /* ---- phase 1: exact per-partition top-16 by (d2, idx) ---- */
    for (int i0 = 0; i0 < KPP; i0 += CHUNK) {
#pragma unroll
        for (int u = 0; u < CHUNK; u++) {
            const int j = jb + i0 + u;
            const float2 kc = kp[j];               /* wave-uniform address: broadcast */
            const float dx = qx - kc.x;
            const float dy = qy - kc.y;
            const float d2 = dx * dx + dy * dy;
            if (d2 < thr) {                        /* strict <: lowest-index tie-break */
                sbuf[wv][cnt][lane] = (((u64)__float_as_uint(d2)) << 32) | (u32)j;
                cnt++;
            }
        }
        if (__any(cnt > CAP - CHUNK)) compact();   /* headroom for next chunk */
    }
    compact();                                     /* slots 0..15 = sorted top-16 */
    __syncthreads();

    /* ---- phase 2: merge partitions, affine scores, softmax (wave 0 only) ---- */
    if (tid < QPB) {
        const int t = tid;
        int p0 = 0, p1 = 0, p2 = 0, p3 = 0;
#pragma unroll
        for (int s = 0; s < KSEL; s++) {
            const u64 v0 = (p0 < KSEL) ? sbuf[0][p0][t] : PADV;
            const u64 v1 = (p1 < KSEL) ? sbuf[1][p1][t] : PADV;
            const u64 v2 = (p2 < KSEL) ? sbuf[2][p2][t] : PADV;
            const u64 v3 = (p3 < KSEL) ? sbuf[3][p3][t] : PADV;
            const u64 m01 = v0 < v1 ? v0 : v1;
            const u64 m23 = v2 < v3 ? v2 : v3;
            const u64 m   = m01 < m23 ? m01 : m23;
            sidx[t * KSEL + s] = (u32)m;           /* global key index */
            p0 += (m == v0); p1 += (m == v1); p2 += (m == v2); p3 += (m == v3);
        }

        /* score_k = A*kx + B*ky + C  (affine reduction of the H=64 projections) */
        float A = 0.f, Bb = 0.f, Cc = 0.f;
        const float2* qwp = (const float2*)qw;
        const float2* kwp = (const float2*)kw;
#pragma unroll 8
        for (int h = 0; h < HD; h++) {
            const float2 a = qwp[h];
            const float qe = qx * a.x + qy * a.y + qbias[h];
            const float2 c = kwp[h];
            A  += qe * c.x;
            Bb += qe * c.y;
            Cc += qe * kbias[h];
        }

        float sc[KSEL];
        float mx = -__builtin_inff();
#pragma unroll
        for (int s = 0; s < KSEL; s++) {
            const float2 kc = kp[sidx[t * KSEL + s]];
            sc[s] = A * kc.x + Bb * kc.y + Cc;
            mx = fmaxf(mx, sc[s]);
        }
        float sum = 0.f;
#pragma unroll
        for (int s = 0; s < KSEL; s++) { sc[s] = expf(sc[s] - mx); sum += sc[s]; }
#pragma unroll
        for (int s = 0; s < KSEL; s++) sw_[t * KSEL + s] = sc[s] / sum;
    }
    __syncthreads();

    /* ---- phase 3: weighted V gather (lane = channel, coalesced 256B rows) ---- */
    const float* vb = vg + (size_t)b * NKEY * CV;
    float* ob = outg + ((size_t)b * NQ + q0) * CV;
    for (int qq = wv; qq < QPB; qq += NWAVE) {
        float acc = 0.f;
#pragma unroll
        for (int s = 0; s < KSEL; s++) {
            const u32 id   = sidx[qq * KSEL + s];  /* wave-uniform LDS read */
            const float wg = sw_[qq * KSEL + s];
            acc = fmaf(wg, vb[(size_t)id * CV + lane], acc);
        }
        ob[qq * CV + lane] = acc;
    }
}

extern "C" void kernel_launch(void* const* d_in, const int* in_sizes, int n_in,
                              void* d_out, int out_size, void* d_ws, size_t ws_size,
                              hipStream_t stream) {
    const float* q  = (const float*)d_in[0];
    const float* k  = (const float*)d_in[1];
    const float* v  = (const float*)d_in[2];
    const float* qw = (const float*)d_in[3];
    const float* qb = (const float*)d_in[4];
    const float* kw = (const float*)d_in[5];
    const float* kb = (const float*)d_in[6];
    /* d_in[7] = top_k (always 16; K is compile-time) */
    float* out = (float*)d_out;

    dim3 grid(NB * (NQ / QPB));   /* 512 blocks */
    dim3 block(256);
    hipLaunchKernelGGL(sparse_bev_attn_kernel, grid, block, 0, stream,
                       q, k, v, qw, qb, kw, kb, out);
}

// Round 2
// 128.219 us; speedup vs baseline: 1.5084x; 1.5084x over previous
//
#include <hip/hip_runtime.h>
#include <stdint.h>

typedef uint64_t u64;
typedef uint32_t u32;

#define NB    8
#define NQ    4096
#define NKEY  4096
#define HD    64
#define CV    64
#define KSEL  16
#define NWAVE 4
#define KPP   (NKEY / NWAVE)   /* 1024 keys per partition-wave */
#define CAP   32               /* 16 sorted + 16 new-candidate slots per lane */
#define QPB   64               /* queries per block (= lanes) */
#define CHUNK 8

/* padding entry: d2=+inf, idx=max  (fp32 bits of nonneg floats are monotone as u32) */
#define PADV ((((u64)0x7F800000u) << 32) | (u64)0xFFFFFFFFu)

__device__ __forceinline__ void ce_asc(u64& a, u64& b) {
    const bool lt = a < b;
    const u64 lo = lt ? a : b;
    const u64 hi = lt ? b : a;
    a = lo; b = hi;
}

/* fully-unrolled bitonic sort-16, ascending (static indices only) */
__device__ __forceinline__ void sort16(u64 v[KSEL]) {
#pragma unroll
    for (int k = 2; k <= KSEL; k <<= 1) {
#pragma unroll
        for (int j = k >> 1; j > 0; j >>= 1) {
#pragma unroll
            for (int i = 0; i < KSEL; i++) {
                const int l = i ^ j;
                if (l > i) {
                    const bool up = ((i & k) == 0);
                    const u64 a = v[i], b = v[l];
                    const bool sw = up ? (a > b) : (a < b);
                    v[i] = sw ? b : a;
                    v[l] = sw ? a : b;
                }
            }
        }
    }
}

/* bitonic merge-16 (input bitonic), ascending */
__device__ __forceinline__ void bmerge16(u64 v[KSEL]) {
#pragma unroll
    for (int j = KSEL >> 1; j > 0; j >>= 1) {
#pragma unroll
        for (int i = 0; i < KSEL; i++) {
            const int l = i ^ j;
            if (l > i) ce_asc(v[i], v[l]);
        }
    }
}

extern "C" __global__ void __launch_bounds__(256, 2)
sparse_bev_attn_kernel(const float* __restrict__ qg,
                       const float* __restrict__ kg,
                       const float* __restrict__ vg,
                       const float* __restrict__ qw,
                       const float* __restrict__ qbias,
                       const float* __restrict__ kw,
                       const float* __restrict__ kbias,
                       float* __restrict__ outg)
{
    /* 64 KB arena: per-wave, per-lane: slots 0..15 = sorted best-16, 16..31 = new.
       Phase-2 overlays sidx/sw onto wave-0 slots 16..31 (dead after final compact). */
    __shared__ u64 sbuf[NWAVE][CAP][QPB];
    __shared__ u32 sthr[QPB];              /* shared per-query threshold (d2 bits) */
    u32*   sidx = (u32*)&sbuf[0][16][0];   /* [QPB][KSEL] = 4 KB */
    float* sw_  = (float*)&sbuf[0][24][0]; /* [QPB][KSEL] = 4 KB */

    const int tid  = threadIdx.x;
    const int wv   = tid >> 6;         /* key partition */
    const int lane = tid & 63;         /* query within block */
    const int b    = blockIdx.x >> 6;
    const int q0   = (blockIdx.x & 63) << 6;
    const int qi   = q0 + lane;

    const float2* kp = (const float2*)(kg + (size_t)b * NKEY * 2);
    const float2  qc = *(const float2*)(qg + ((size_t)b * NQ + qi) * 2);
    const float qx = qc.x, qy = qc.y;

    if (tid < QPB) sthr[tid] = 0x7F800000u;           /* +inf */
    /* init sorted region to PAD (wave-private, lane-private column) */
#pragma unroll
    for (int s = 0; s < KSEL; s++) sbuf[wv][s][lane] = PADV;
    __syncthreads();

    const int jb = __builtin_amdgcn_readfirstlane(wv * KPP);
    const float2* kpart = kp + jb;                    /* uniform base -> s_load */

    int newcnt = 0;

    auto compact = [&]() {
        u64 nw[KSEL];
#pragma unroll
        for (int s = 0; s < KSEL; s++) {
            const u64 x = sbuf[wv][KSEL + s][lane];   /* stale slots masked below */
            nw[s] = (s < newcnt) ? x : PADV;
        }
        sort16(nw);                                   /* ascending */
        u64 m[KSEL];
#pragma unroll
        for (int i = 0; i < KSEL; i++) {
            const u64 a = sbuf[wv][i][lane];          /* sorted ascending */
            const u64 c = nw[KSEL - 1 - i];
            m[i] = a < c ? a : c;                     /* lowest-16 of union, bitonic */
        }
        bmerge16(m);
#pragma unroll
        for (int s = 0; s < KSEL; s++) sbuf[wv][s][lane] = m[s];
        newcnt = 0;
        atomicMin(&sthr[lane], (u32)(m[KSEL - 1] >> 32));
    };

    auto process = [&](const float2 c[CHUNK], int base) {
        const float thr = __uint_as_float(sthr[lane]);
#pragma unroll
        for (int u = 0; u < CHUNK; u++) {
            const float dx = qx - c[u].x;
            const float dy = qy - c[u].y;
            const float d2 = fmaf(dx, dx, dy * dy);
            if (d2 <= thr) {                          /* <=: keep boundary ties */
                sbuf[wv][KSEL + newcnt][lane] =
                    (((u64)__float_as_uint(d2)) << 32) | (u32)(jb + base + u);
                newcnt++;
            }
        }
    };

    /* ---- phase 1: exact per-partition top-16 by (d2, idx), shared pruning ---- */
    float2 c0[CHUNK], c1[CHUNK];
#pragma unroll
    for (int u = 0; u < CHUNK; u++) c0[u] = kpart[u];
    for (int i0 = 0; i0 < KPP; i0 += 2 * CHUNK) {
#pragma unroll
        for (int u = 0; u < CHUNK; u++) c1[u] = kpart[i0 + CHUNK + u];
        process(c0, i0);
        if (__any(newcnt > CHUNK)) compact();
        if (i0 + 2 * CHUNK < KPP) {
#pragma unroll
            for (int u = 0; u < CHUNK; u++) c0[u] = kpart[i0 + 2 * CHUNK + u];
        }
        process(c1, i0 + CHUNK);
        if (__any(newcnt > CHUNK)) compact();
    }
    compact();                                        /* slots 0..15 = sorted top-16 */
    __syncthreads();

    /* ---- phase 2: merge partitions, affine scores, softmax (wave 0 only) ---- */
    if (tid < QPB) {
        const int t = tid;
        int p0 = 0, p1 = 0, p2 = 0, p3 = 0;
#pragma unroll
        for (int s = 0; s < KSEL; s++) {
            const u64 v0 = (p0 < KSEL) ? sbuf[0][p0][t] : PADV;
            const u64 v1 = (p1 < KSEL) ? sbuf[1][p1][t] : PADV;
            const u64 v2 = (p2 < KSEL) ? sbuf[2][p2][t] : PADV;
            const u64 v3 = (p3 < KSEL) ? sbuf[3][p3][t] : PADV;
            const u64 m01 = v0 < v1 ? v0 : v1;
            const u64 m23 = v2 < v3 ? v2 : v3;
            const u64 m   = m01 < m23 ? m01 : m23;
            sidx[t * KSEL + s] = (u32)m;              /* global key index */
            p0 += (m == v0); p1 += (m == v1); p2 += (m == v2); p3 += (m == v3);
        }

        /* score_k = A*kx + B*ky + C  (affine reduction of the H=64 projections) */
        float A = 0.f, Bb = 0.f, Cc = 0.f;
        const float2* qwp = (const float2*)qw;
        const float2* kwp = (const float2*)kw;
#pragma unroll 8
        for (int h = 0; h < HD; h++) {
            const float2 a = qwp[h];
            const float qe = qx * a.x + qy * a.y + qbias[h];
            const float2 c = kwp[h];
            A  += qe * c.x;
            Bb += qe * c.y;
            Cc += qe * kbias[h];
        }

        float sc[KSEL];
        float mx = -__builtin_inff();
#pragma unroll
        for (int s = 0; s < KSEL; s++) {
            const float2 kc = kp[sidx[t * KSEL + s]];
            sc[s] = A * kc.x + Bb * kc.y + Cc;
            mx = fmaxf(mx, sc[s]);
        }
        float sum = 0.f;
#pragma unroll
        for (int s = 0; s < KSEL; s++) { sc[s] = expf(sc[s] - mx); sum += sc[s]; }
#pragma unroll
        for (int s = 0; s < KSEL; s++) sw_[t * KSEL + s] = sc[s] / sum;
    }
    __syncthreads();

    /* ---- phase 3: weighted V gather (lane = channel, coalesced 256B rows) ---- */
    const float* vb = vg + (size_t)b * NKEY * CV;
    float* ob = outg + ((size_t)b * NQ + q0) * CV;
    for (int qq = wv; qq < QPB; qq += NWAVE) {
        float acc = 0.f;
#pragma unroll
        for (int s = 0; s < KSEL; s++) {
            const u32 id   = sidx[qq * KSEL + s];     /* wave-uniform LDS read */
            const float wg = sw_[qq * KSEL + s];
            acc = fmaf(wg, vb[(size_t)id * CV + lane], acc);
        }
        ob[qq * CV + lane] = acc;
    }
}

extern "C" void kernel_launch(void* const* d_in, const int* in_sizes, int n_in,
                              void* d_out, int out_size, void* d_ws, size_t ws_size,
                              hipStream_t stream) {
    const float* q  = (const float*)d_in[0];
    const float* k  = (const float*)d_in[1];
    const float* v  = (const float*)d_in[2];
    const float* qw = (const float*)d_in[3];
    const float* qb = (const float*)d_in[4];
    const float* kw = (const float*)d_in[5];
    const float* kb = (const float*)d_in[6];
    /* d_in[7] = top_k (always 16; K is compile-time) */
    float* out = (float*)d_out;

    dim3 grid(NB * (NQ / QPB));   /* 512 blocks */
    dim3 block(256);
    hipLaunchKernelGGL(sparse_bev_attn_kernel, grid, block, 0, stream,
                       q, k, v, qw, qb, kw, kb, out);
}

// Round 3
// 115.901 us; speedup vs baseline: 1.6687x; 1.1063x over previous
//
#include <hip/hip_runtime.h>
#include <stdint.h>

typedef uint64_t u64;
typedef uint32_t u32;

#define NB    8
#define NQ    4096
#define NKEY  4096
#define HD    64
#define CV    64
#define KSEL  16
#define NWAVE 8
#define KPP   (NKEY / NWAVE)   /* 512 keys per partition-wave */
#define QPB   64               /* queries per block (= lanes) */
#define BLK   (NWAVE * 64)     /* 512 threads */

/* padding entry: d2=+inf, idx=max  (fp32 bits of nonneg floats are monotone as u32) */
#define PADV ((((u64)0x7F800000u) << 32) | (u64)0xFFFFFFFFu)

__device__ __forceinline__ void ce_asc(u64& a, u64& b) {
    const bool lt = a < b;
    const u64 lo = lt ? a : b;
    const u64 hi = lt ? b : a;
    a = lo; b = hi;
}

/* fully-unrolled bitonic sort-16, ascending (static indices only) */
__device__ __forceinline__ void sort16(u64 v[KSEL]) {
#pragma unroll
    for (int k = 2; k <= KSEL; k <<= 1) {
#pragma unroll
        for (int j = k >> 1; j > 0; j >>= 1) {
#pragma unroll
            for (int i = 0; i < KSEL; i++) {
                const int l = i ^ j;
                if (l > i) {
                    const bool up = ((i & k) == 0);
                    const u64 a = v[i], b = v[l];
                    const bool sw = up ? (a > b) : (a < b);
                    v[i] = sw ? b : a;
                    v[l] = sw ? a : b;
                }
            }
        }
    }
}

/* bitonic merge-16 (input bitonic), ascending */
__device__ __forceinline__ void bmerge16(u64 v[KSEL]) {
#pragma unroll
    for (int j = KSEL >> 1; j > 0; j >>= 1) {
#pragma unroll
        for (int i = 0; i < KSEL; i++) {
            const int l = i ^ j;
            if (l > i) ce_asc(v[i], v[l]);
        }
    }
}

extern "C" __global__ void __launch_bounds__(BLK, 4)
sparse_bev_attn_kernel(const float* __restrict__ qg,
                       const float* __restrict__ kg,
                       const float* __restrict__ vg,
                       const float* __restrict__ qw,
                       const float* __restrict__ qbias,
                       const float* __restrict__ kw,
                       const float* __restrict__ kbias,
                       float* __restrict__ outg)
{
    /* 64 KB: per-wave per-lane 16-slot new-candidate buffers; final per-wave
       sorted-16 lists are written here too. Phase-2 output (sidx/sw) overlays
       nbuf[0] after its reads complete (guarded by a barrier). */
    __shared__ u64 nbuf[NWAVE][KSEL][QPB];
    __shared__ u32 sthr[QPB];                     /* shared per-query 16th-best d2 bits */
    u32*   sidx = (u32*)&nbuf[0][0][0];           /* [QPB][KSEL] = 4 KB */
    float* sw_  = (float*)((char*)&nbuf[0][0][0] + 4096); /* [QPB][KSEL] = 4 KB */

    const int tid  = threadIdx.x;
    const int wv   = tid >> 6;                    /* key partition */
    const int lane = tid & 63;                    /* query within block */
    const int b    = blockIdx.x >> 6;
    const int q0   = (blockIdx.x & 63) << 6;
    const int qi   = q0 + lane;

    const float2* kp = (const float2*)(kg + (size_t)b * NKEY * 2);
    const float2  qc = *(const float2*)(qg + ((size_t)b * NQ + qi) * 2);
    const float qx = qc.x, qy = qc.y;

    if (tid < QPB) sthr[tid] = 0x7F800000u;       /* +inf */
    __syncthreads();

    const int jb = __builtin_amdgcn_readfirstlane(wv * KPP);
    const float4* kp4 = (const float4*)(kp + jb); /* uniform base; 2 keys per float4 */

    /* ---- seed best[] from the first 16 keys (valid threshold upper bound) ---- */
    u64 best[KSEL];
    u32 thrbits;
    {
#pragma unroll
        for (int u = 0; u < 8; u++) {
            const float4 kk = kp4[u];
            const float dx0 = qx - kk.x, dy0 = qy - kk.y;
            const float dx1 = qx - kk.z, dy1 = qy - kk.w;
            const float d20 = fmaf(dx0, dx0, dy0 * dy0);
            const float d21 = fmaf(dx1, dx1, dy1 * dy1);
            best[2 * u]     = (((u64)__float_as_uint(d20)) << 32) | (u32)(jb + 2 * u);
            best[2 * u + 1] = (((u64)__float_as_uint(d21)) << 32) | (u32)(jb + 2 * u + 1);
        }
        sort16(best);
        thrbits = (u32)(best[KSEL - 1] >> 32);
        atomicMin(&sthr[lane], thrbits);
    }

    int newcnt = 0;
    u64* nb0 = &nbuf[wv][0][lane];                /* slot s at nb0[s*QPB] */

    auto compact = [&]() {
        u64 nw[KSEL];
#pragma unroll
        for (int s = 0; s < KSEL; s++) {
            const u64 x = nb0[s * QPB];           /* stale slots masked below */
            nw[s] = (s < newcnt) ? x : PADV;
        }
        sort16(nw);                               /* ascending */
#pragma unroll
        for (int i = 0; i < KSEL; i++) {          /* lowest-16 of union -> bitonic */
            const u64 c = nw[KSEL - 1 - i];
            best[i] = best[i] < c ? best[i] : c;
        }
        bmerge16(best);
        newcnt = 0;
        const u32 nbits = (u32)(best[KSEL - 1] >> 32);
        const u32 old = atomicMin(&sthr[lane], nbits);
        thrbits = old < nbits ? old : nbits;
    };

    auto eval = [&](float kx, float ky, int idx) {
        const float dx = qx - kx, dy = qy - ky;
        const float d2 = fmaf(dx, dx, dy * dy);
        if (d2 <= __uint_as_float(thrbits)) {     /* <=: keep boundary ties */
            nb0[newcnt * QPB] = (((u64)__float_as_uint(d2)) << 32) | (u32)idx;
            newcnt++;
        }
    };

    /* ---- phase 1: exact per-partition top-16 by (d2, idx), shared pruning ----
       thr is prefetched one iteration ahead so the ds_read latency hides. */
    u32 tbpref = ((volatile u32*)sthr)[lane];
    for (int i0 = KSEL; i0 < KPP; i0 += 16) {
        thrbits = thrbits < tbpref ? thrbits : tbpref;
        tbpref = ((volatile u32*)sthr)[lane];
        const float4* p4 = (const float4*)(kp + jb + i0);
#pragma unroll
        for (int u = 0; u < 4; u++) {
            const float4 kk = p4[u];
            eval(kk.x, kk.y, jb + i0 + 2 * u);
            eval(kk.z, kk.w, jb + i0 + 2 * u + 1);
        }
        if (__any(newcnt > 8)) compact();
#pragma unroll
        for (int u = 4; u < 8; u++) {
            const float4 kk = p4[u];
            eval(kk.x, kk.y, jb + i0 + 2 * u);
            eval(kk.z, kk.w, jb + i0 + 2 * u + 1);
        }
        if (__any(newcnt > 8)) compact();
    }
    if (__any(newcnt > 0)) compact();

    /* publish per-wave sorted top-16 */
#pragma unroll
    for (int s = 0; s < KSEL; s++) nb0[s * QPB] = best[s];
    __syncthreads();

    /* ---- phase 2: 8-way merge, affine scores, softmax (wave 0 only) ---- */
    u64 msel[KSEL];
    float wsm[KSEL];
    if (tid < QPB) {
        const int t = tid;
        int p[NWAVE];
#pragma unroll
        for (int w = 0; w < NWAVE; w++) p[w] = 0;
#pragma unroll
        for (int s = 0; s < KSEL; s++) {
            u64 vv[NWAVE];
            u64 m = PADV;
#pragma unroll
            for (int w = 0; w < NWAVE; w++) {
                const u64 x = (p[w] < KSEL) ? nbuf[w][p[w]][t] : PADV;
                vv[w] = x;
                m = x < m ? x : m;
            }
#pragma unroll
            for (int w = 0; w < NWAVE; w++) p[w] += (vv[w] == m);
            msel[s] = m;
        }

        /* score_k = A*kx + B*ky + C  (affine reduction of the H=64 projections) */
        float A = 0.f, Bb = 0.f, Cc = 0.f;
        const float2* qwp = (const float2*)qw;
        const float2* kwp = (const float2*)kw;
#pragma unroll 8
        for (int h = 0; h < HD; h++) {
            const float2 a = qwp[h];
            const float qe = fmaf(qx, a.x, fmaf(qy, a.y, qbias[h]));
            const float2 c = kwp[h];
            A  = fmaf(qe, c.x, A);
            Bb = fmaf(qe, c.y, Bb);
            Cc = fmaf(qe, kbias[h], Cc);
        }

        float sc[KSEL];
        float mx = -__builtin_inff();
#pragma unroll
        for (int s = 0; s < KSEL; s++) {
            const float2 kc = kp[(u32)msel[s]];
            sc[s] = fmaf(A, kc.x, fmaf(Bb, kc.y, Cc));
            mx = fmaxf(mx, sc[s]);
        }
        float sum = 0.f;
#pragma unroll
        for (int s = 0; s < KSEL; s++) { sc[s] = expf(sc[s] - mx); sum += sc[s]; }
        const float inv = 1.f / sum;
#pragma unroll
        for (int s = 0; s < KSEL; s++) wsm[s] = sc[s] * inv;
    }
    __syncthreads();                              /* nbuf reads done before overlay */
    if (tid < QPB) {
#pragma unroll
        for (int s = 0; s < KSEL; s++) {
            sidx[tid * KSEL + s] = (u32)msel[s];
            sw_ [tid * KSEL + s] = wsm[s];
        }
    }
    __syncthreads();

    /* ---- phase 3: weighted V gather (lane = channel, coalesced 256B rows) ---- */
    const float* vb = vg + (size_t)b * NKEY * CV;
    float* ob = outg + ((size_t)b * NQ + q0) * CV;
    for (int qq = wv; qq < QPB; qq += NWAVE) {
        float acc = 0.f;
#pragma unroll
        for (int s = 0; s < KSEL; s++) {
            const u32 id   = sidx[qq * KSEL + s]; /* wave-uniform LDS read */
            const float wg = sw_[qq * KSEL + s];
            acc = fmaf(wg, vb[(size_t)id * CV + lane], acc);
        }
        ob[qq * CV + lane] = acc;
    }
}

extern "C" void kernel_launch(void* const* d_in, const int* in_sizes, int n_in,
                              void* d_out, int out_size, void* d_ws, size_t ws_size,
                              hipStream_t stream) {
    const float* q  = (const float*)d_in[0];
    const float* k  = (const float*)d_in[1];
    const float* v  = (const float*)d_in[2];
    const float* qw = (const float*)d_in[3];
    const float* qb = (const float*)d_in[4];
    const float* kw = (const float*)d_in[5];
    const float* kb = (const float*)d_in[6];
    /* d_in[7] = top_k (always 16; K is compile-time) */
    float* out = (float*)d_out;

    dim3 grid(NB * (NQ / QPB));   /* 512 blocks */
    dim3 block(BLK);              /* 512 threads = 8 waves */
    hipLaunchKernelGGL(sparse_bev_attn_kernel, grid, block, 0, stream,
                       q, k, v, qw, qb, kw, kb, out);
}